// Round 3
// baseline (21.934 us; speedup 1.0000x reference)
//
#include <hip/hip_runtime.h>
#include <math.h>

#define DEGREE 20
#define NW (DEGREE + 1)
#define INV_4PI 0.07957747154594767f  // 1/(4*pi): angle t*x -> t*x/2 in revolutions

// float layout inside d_ws
#define OFF_SC 0    // 40 floats: (sp_k, sm_k) per layer k=0..19
#define OFF_WI 40   // 8 floats: w_init complex[4]  = T * (W_0 e0)
#define OFF_RT 48   // 8 floats: r_tilde complex[4] = row0(W_20) * T
#define OFF_WT 56   // 19*32 floats: Wtilde_k = T W_k T for k=1..19, row-major complex

// ---------- complex helpers ----------
__device__ __forceinline__ float2 cmul(float2 a, float2 b) {
    return make_float2(a.x * b.x - a.y * b.y, a.x * b.y + a.y * b.x);
}
__device__ __forceinline__ float2 cfma(float2 a, float2 b, float2 acc) {
    acc.x = fmaf(a.x, b.x, fmaf(-a.y, b.y, acc.x));
    acc.y = fmaf(a.x, b.y, fmaf(a.y, b.x, acc.y));
    return acc;
}

// A = RZ(t2) @ RY(t1) @ RX(t0), 2x2 complex (one-time, accurate trig)
__device__ void build_su2(float t0, float t1, float t2, float2 A[2][2]) {
    float c0 = cosf(0.5f * t0), s0 = sinf(0.5f * t0);
    float c1 = cosf(0.5f * t1), s1 = sinf(0.5f * t1);
    float c2 = cosf(0.5f * t2), s2 = sinf(0.5f * t2);
    float2 RX[2][2] = {{{c0, 0.f}, {0.f, -s0}}, {{0.f, -s0}, {c0, 0.f}}};
    float2 RY[2][2] = {{{c1, 0.f}, {-s1, 0.f}}, {{s1, 0.f}, {c1, 0.f}}};
    float2 RZ[2][2] = {{{c2, -s2}, {0.f, 0.f}}, {{0.f, 0.f}, {c2, s2}}};
    float2 T[2][2];
    for (int i = 0; i < 2; ++i)
        for (int j = 0; j < 2; ++j) {
            float2 acc = {0.f, 0.f};
            for (int k = 0; k < 2; ++k) acc = cfma(RY[i][k], RX[k][j], acc);
            T[i][j] = acc;
        }
    for (int i = 0; i < 2; ++i)
        for (int j = 0; j < 2; ++j) {
            float2 acc = {0.f, 0.f};
            for (int k = 0; k < 2; ++k) acc = cfma(RZ[i][k], T[k][j], acc);
            A[i][j] = acc;
        }
}

// One tiny block: precompute transformed tables into P (d_ws).
__global__ void build_pre(const float* __restrict__ theta,
                          const float* __restrict__ phi,
                          float* __restrict__ P) {
    const float T4[4][4] = {{.5f, .5f, .5f, .5f},
                            {.5f, -.5f, .5f, -.5f},
                            {.5f, .5f, -.5f, -.5f},
                            {.5f, -.5f, -.5f, .5f}};  // H (x) H, symmetric, T^2=I
    int t = threadIdx.x;
    if (t == 21) {
        for (int k = 0; k < DEGREE; ++k) {
            P[OFF_SC + 2 * k] = (theta[2 * k] + theta[2 * k + 1]) * INV_4PI;
            P[OFF_SC + 2 * k + 1] = (theta[2 * k] - theta[2 * k + 1]) * INV_4PI;
        }
    }
    if (t < NW) {
        const float* p = phi + 6 * t;
        float2 A[2][2], B[2][2];
        build_su2(p[0], p[1], p[2], A);
        build_su2(p[3], p[4], p[5], B);
        float2 W[4][4];
        for (int i = 0; i < 2; ++i)
            for (int pp = 0; pp < 2; ++pp)
                for (int j = 0; j < 2; ++j)
                    for (int q = 0; q < 2; ++q) {
                        int r = 2 * i + pp, c = 2 * j + q;
                        float2 m = cmul(A[i][j], B[pp][q]);
                        if (r == 3) { m.x = -m.x; m.y = -m.y; }  // CZ (row 3)
                        W[r][c] = m;
                    }
        if (t == 0) {
            // w_init[j] = sum_c T[j][c] * W[c][0]
            for (int j = 0; j < 4; ++j) {
                float2 acc = {0.f, 0.f};
                for (int c = 0; c < 4; ++c) {
                    acc.x += T4[j][c] * W[c][0].x;
                    acc.y += T4[j][c] * W[c][0].y;
                }
                P[OFF_WI + 2 * j] = acc.x;
                P[OFF_WI + 2 * j + 1] = acc.y;
            }
        } else if (t == DEGREE) {
            // r_tilde[c] = sum_a W[0][a] * T[a][c]
            for (int c = 0; c < 4; ++c) {
                float2 acc = {0.f, 0.f};
                for (int a = 0; a < 4; ++a) {
                    acc.x += W[0][a].x * T4[a][c];
                    acc.y += W[0][a].y * T4[a][c];
                }
                P[OFF_RT + 2 * c] = acc.x;
                P[OFF_RT + 2 * c + 1] = acc.y;
            }
        } else {
            // Wtilde = T * W * T
            float2 Q[4][4];
            for (int r = 0; r < 4; ++r)
                for (int c = 0; c < 4; ++c) {
                    float2 acc = {0.f, 0.f};
                    for (int b = 0; b < 4; ++b) {
                        acc.x += W[r][b].x * T4[b][c];
                        acc.y += W[r][b].y * T4[b][c];
                    }
                    Q[r][c] = acc;
                }
            float* dst = P + OFF_WT + (t - 1) * 32;
            for (int r = 0; r < 4; ++r)
                for (int c = 0; c < 4; ++c) {
                    float2 acc = {0.f, 0.f};
                    for (int a = 0; a < 4; ++a) {
                        acc.x += T4[r][a] * Q[a][c].x;
                        acc.y += T4[r][a] * Q[a][c].y;
                    }
                    dst[(r * 4 + c) * 2] = acc.x;
                    dst[(r * 4 + c) * 2 + 1] = acc.y;
                }
        }
    }
}

// hardware sin/cos: input in revolutions (v_sin_f32: D = sin(S0 * 2pi))
__device__ __forceinline__ float hw_sin(float rev) {
    float r;
    asm("v_sin_f32 %0, %1" : "=v"(r) : "v"(rev));
    return r;
}
__device__ __forceinline__ float hw_cos(float rev) {
    float r;
    asm("v_cos_f32 %0, %1" : "=v"(r) : "v"(rev));
    return r;
}

__global__ __launch_bounds__(256) void dqc1_main(
    const float* __restrict__ x, const float* __restrict__ P,
    float* __restrict__ out, int n) {
    int gid = blockIdx.x * blockDim.x + threadIdx.x;
    if (gid >= n) return;
    float xv = x[gid];

    float wr[4], wi[4];
    {
        // k = 0: w = D_0 * w_init   (W_0 already folded into w_init)
        float rp = P[OFF_SC + 0] * xv, rm = P[OFF_SC + 1] * xv;
        float cp = hw_cos(rp), sp_ = hw_sin(rp);
        float cm = hw_cos(rm), sm_ = hw_sin(rm);
        float a, b;
        a = P[OFF_WI + 0]; b = P[OFF_WI + 1];  // d0 = (cp, -sp)
        wr[0] = fmaf(cp, a, sp_ * b); wi[0] = fmaf(cp, b, -sp_ * a);
        a = P[OFF_WI + 2]; b = P[OFF_WI + 3];  // d1 = (cm, -sm)
        wr[1] = fmaf(cm, a, sm_ * b); wi[1] = fmaf(cm, b, -sm_ * a);
        a = P[OFF_WI + 4]; b = P[OFF_WI + 5];  // conj(d1)
        wr[2] = fmaf(cm, a, -sm_ * b); wi[2] = fmaf(cm, b, sm_ * a);
        a = P[OFF_WI + 6]; b = P[OFF_WI + 7];  // conj(d0)
        wr[3] = fmaf(cp, a, -sp_ * b); wi[3] = fmaf(cp, b, sp_ * a);
    }

#pragma unroll
    for (int k = 1; k < DEGREE; ++k) {
        // issue trig early so TRANS latency hides under the matvec
        float rp = P[OFF_SC + 2 * k] * xv, rm = P[OFF_SC + 2 * k + 1] * xv;
        float cp = hw_cos(rp), sp_ = hw_sin(rp);
        float cm = hw_cos(rm), sm_ = hw_sin(rm);

        // n = Wtilde_k * w   (uniform W entries -> SGPR operands)
        const float* Wk = P + OFF_WT + (k - 1) * 32;
        float nr[4], ni[4];
#pragma unroll
        for (int i = 0; i < 4; ++i) {
            const float* R = Wk + i * 8;
            float nx = R[0] * wr[0];
            nx = fmaf(-R[1], wi[0], nx);
            float ny = R[0] * wi[0];
            ny = fmaf(R[1], wr[0], ny);
#pragma unroll
            for (int j = 1; j < 4; ++j) {
                nx = fmaf(R[2 * j], wr[j], nx);
                nx = fmaf(-R[2 * j + 1], wi[j], nx);
                ny = fmaf(R[2 * j], wi[j], ny);
                ny = fmaf(R[2 * j + 1], wr[j], ny);
            }
            nr[i] = nx; ni[i] = ny;
        }

        // w = D_k * n
        wr[0] = fmaf(cp, nr[0], sp_ * ni[0]); wi[0] = fmaf(cp, ni[0], -sp_ * nr[0]);
        wr[1] = fmaf(cm, nr[1], sm_ * ni[1]); wi[1] = fmaf(cm, ni[1], -sm_ * nr[1]);
        wr[2] = fmaf(cm, nr[2], -sm_ * ni[2]); wi[2] = fmaf(cm, ni[2], sm_ * nr[2]);
        wr[3] = fmaf(cp, nr[3], -sp_ * ni[3]); wi[3] = fmaf(cp, ni[3], sp_ * nr[3]);
    }

    // ans = Re( r_tilde . w )
    float ans = P[OFF_RT + 0] * wr[0];
    ans = fmaf(-P[OFF_RT + 1], wi[0], ans);
    ans = fmaf(P[OFF_RT + 2], wr[1], ans);
    ans = fmaf(-P[OFF_RT + 3], wi[1], ans);
    ans = fmaf(P[OFF_RT + 4], wr[2], ans);
    ans = fmaf(-P[OFF_RT + 5], wi[2], ans);
    ans = fmaf(P[OFF_RT + 6], wr[3], ans);
    ans = fmaf(-P[OFF_RT + 7], wi[3], ans);
    out[gid] = ans;
}

extern "C" void kernel_launch(void* const* d_in, const int* in_sizes, int n_in,
                              void* d_out, int out_size, void* d_ws, size_t ws_size,
                              hipStream_t stream) {
    const float* x = (const float*)d_in[0];      // [N]
    const float* theta = (const float*)d_in[1];  // [20][2]
    const float* phi = (const float*)d_in[2];    // [21][6]
    float* out = (float*)d_out;
    int n = in_sizes[0];
    float* P = (float*)d_ws;  // 664 floats

    build_pre<<<1, 32, 0, stream>>>(theta, phi, P);
    int block = 256;
    int grid = (n + block - 1) / block;
    dqc1_main<<<grid, block, 0, stream>>>(x, P, out, n);
}